// Round 1
// baseline (24031.404 us; speedup 1.0000x reference)
//
#include <hip/hip_runtime.h>

typedef __attribute__((ext_vector_type(8))) short short8;
typedef __attribute__((ext_vector_type(8))) __bf16 bf16x8;
typedef __attribute__((ext_vector_type(4))) float f32x4;

#define GENF 100
#define TCOND 50
#define BATCH 128
#define HID 1024
#define INP 171
#define INPAD 192
#define OUTN 171
#define OUTPAD 176

static __device__ __forceinline__ unsigned short f2bf(float f) {
  unsigned u = __builtin_bit_cast(unsigned, f);
  u += 0x7fffu + ((u >> 16) & 1u);
  return (unsigned short)(u >> 16);
}
static __device__ __forceinline__ float bf2f(unsigned short s) {
  unsigned u = ((unsigned)s) << 16;
  return __builtin_bit_cast(float, u);
}
static __device__ __forceinline__ bf16x8 ld8(const unsigned short* p) {
  short8 v = *reinterpret_cast<const short8*>(p);
  return __builtin_bit_cast(bf16x8, v);
}
static __device__ __forceinline__ float sigm(float x) { return 1.f / (1.f + __expf(-x)); }

// Accumulate acc[g] += A * W_g^T for 4 gates, with bf16x3 precision:
// A = ahi+alo, W = bhi+blo; compute ahi*bhi + alo*bhi + ahi*blo.
// A: [128][lda] bf16 (hi/lo). W: [4*HID][ldb] bf16 (hi/lo), gate g rows at g*HID.
static __device__ __forceinline__ void mm3g(
    f32x4 acc[4],
    const unsigned short* __restrict__ ahi, const unsigned short* __restrict__ alo, int lda,
    const unsigned short* __restrict__ bhi, const unsigned short* __restrict__ blo, int ldb,
    int K, int m0, int n0, int lane)
{
  const int row = lane & 15, kg = lane >> 4;
  const unsigned short* pah = ahi + (size_t)(m0 + row) * lda + kg * 8;
  const unsigned short* pal = alo + (size_t)(m0 + row) * lda + kg * 8;
  const unsigned short* pbh[4];
  const unsigned short* pbl[4];
#pragma unroll
  for (int g = 0; g < 4; ++g) {
    pbh[g] = bhi + (size_t)(g * HID + n0 + row) * ldb + kg * 8;
    pbl[g] = blo + (size_t)(g * HID + n0 + row) * ldb + kg * 8;
  }
  for (int k0 = 0; k0 < K; k0 += 32) {
    bf16x8 a1 = ld8(pah + k0);
    bf16x8 a2 = ld8(pal + k0);
#pragma unroll
    for (int g = 0; g < 4; ++g) {
      bf16x8 b1 = ld8(pbh[g] + k0);
      bf16x8 b2 = ld8(pbl[g] + k0);
      acc[g] = __builtin_amdgcn_mfma_f32_16x16x32_bf16(a1, b1, acc[g], 0, 0, 0);
      acc[g] = __builtin_amdgcn_mfma_f32_16x16x32_bf16(a2, b1, acc[g], 0, 0, 0);
      acc[g] = __builtin_amdgcn_mfma_f32_16x16x32_bf16(a1, b2, acc[g], 0, 0, 0);
    }
  }
}

// One LSTM layer step, fused GEMM(4 gates) + cell update.
// Grid: 512 blocks x 64 threads. Block wid: n-group = wid&63 (16 cols), m-group = wid>>6 (16 rows).
__global__ __launch_bounds__(64) void lstm_layer_k(
    const unsigned short* __restrict__ xhi, const unsigned short* __restrict__ xlo, int ldx, int Kx,
    const unsigned short* __restrict__ wxhi, const unsigned short* __restrict__ wxlo,
    const unsigned short* __restrict__ hhi, const unsigned short* __restrict__ hlo,
    const unsigned short* __restrict__ whhi, const unsigned short* __restrict__ whlo,
    const float* __restrict__ bias,
    float* __restrict__ c,
    unsigned short* __restrict__ ohhi, unsigned short* __restrict__ ohlo)
{
  const int lane = threadIdx.x;
  const int wid = blockIdx.x;
  const int n0 = (wid & 63) * 16;
  const int m0 = (wid >> 6) * 16;
  f32x4 z = {0.f, 0.f, 0.f, 0.f};
  f32x4 acc[4] = {z, z, z, z};
  mm3g(acc, xhi, xlo, ldx, wxhi, wxlo, Kx, Kx, m0, n0, lane);
  mm3g(acc, hhi, hlo, HID, whhi, whlo, HID, HID, m0, n0, lane);
  // C/D layout: col = lane&15, row = (lane>>4)*4 + r
  const int col = lane & 15, rg = lane >> 4;
#pragma unroll
  for (int r = 0; r < 4; ++r) {
    int m = m0 + rg * 4 + r;
    int n = n0 + col;
    float gi = sigm(acc[0][r] + bias[n]);
    float gf = sigm(acc[1][r] + bias[HID + n]);
    float gg = tanhf(acc[2][r] + bias[2 * HID + n]);
    float go = sigm(acc[3][r] + bias[3 * HID + n]);
    size_t idx = (size_t)m * HID + n;
    float cn = gf * c[idx] + gi * gg;
    c[idx] = cn;
    float h = go * tanhf(cn);
    unsigned short hh = f2bf(h);
    ohhi[idx] = hh;
    ohlo[idx] = f2bf(h - bf2f(hh));
  }
}

// Decoder: out = h2 @ w_dec^T + b_dec. Writes fp32 to d_out (if outp != null)
// and next-frame hi/lo bf16 (padded to INPAD with zeros kept from init memset).
__global__ __launch_bounds__(64) void dec_k(
    const unsigned short* __restrict__ hhi, const unsigned short* __restrict__ hlo,
    const unsigned short* __restrict__ wdhi, const unsigned short* __restrict__ wdlo,
    const float* __restrict__ bd,
    float* __restrict__ outp,
    unsigned short* __restrict__ fxhi, unsigned short* __restrict__ fxlo)
{
  const int lane = threadIdx.x;
  const int wid = blockIdx.x;
  const int n0 = (wid % 11) * 16;
  const int m0 = (wid / 11) * 16;
  const int row = lane & 15, kg = lane >> 4;
  f32x4 acc = {0.f, 0.f, 0.f, 0.f};
  const unsigned short* pah = hhi + (size_t)(m0 + row) * HID + kg * 8;
  const unsigned short* pal = hlo + (size_t)(m0 + row) * HID + kg * 8;
  const unsigned short* pbh = wdhi + (size_t)(n0 + row) * HID + kg * 8;
  const unsigned short* pbl = wdlo + (size_t)(n0 + row) * HID + kg * 8;
  for (int k0 = 0; k0 < HID; k0 += 32) {
    bf16x8 a1 = ld8(pah + k0), a2 = ld8(pal + k0);
    bf16x8 b1 = ld8(pbh + k0), b2 = ld8(pbl + k0);
    acc = __builtin_amdgcn_mfma_f32_16x16x32_bf16(a1, b1, acc, 0, 0, 0);
    acc = __builtin_amdgcn_mfma_f32_16x16x32_bf16(a2, b1, acc, 0, 0, 0);
    acc = __builtin_amdgcn_mfma_f32_16x16x32_bf16(a1, b2, acc, 0, 0, 0);
  }
  const int col = lane & 15, rg = lane >> 4;
#pragma unroll
  for (int r = 0; r < 4; ++r) {
    int m = m0 + rg * 4 + r;
    int n = n0 + col;
    if (n < OUTN) {
      float v = acc[r] + bd[n];
      if (outp) outp[(size_t)m * (GENF * OUTN) + n] = v;
      unsigned short vh = f2bf(v);
      fxhi[(size_t)m * INPAD + n] = vh;
      fxlo[(size_t)m * INPAD + n] = f2bf(v - bf2f(vh));
    }
  }
}

// ---- prep kernels ----
__global__ void cvt_hilo_k(const float* __restrict__ src, unsigned short* __restrict__ hi,
                           unsigned short* __restrict__ lo, int R, int C, int Rp, int Cp)
{
  int idx = blockIdx.x * 256 + threadIdx.x;
  if (idx >= Rp * Cp) return;
  int r = idx / Cp, c2 = idx - r * Cp;
  float v = (r < R && c2 < C) ? src[(size_t)r * C + c2] : 0.f;
  unsigned short h = f2bf(v);
  hi[idx] = h;
  lo[idx] = f2bf(v - bf2f(h));
}

__global__ void bias2_k(const float* __restrict__ a, const float* __restrict__ b,
                        float* __restrict__ dst, int n)
{
  int i = blockIdx.x * 256 + threadIdx.x;
  if (i < n) dst[i] = a[i] + b[i];
}

__global__ void biaspad_k(const float* __restrict__ a, float* __restrict__ dst, int n, int np)
{
  int i = blockIdx.x * 256 + threadIdx.x;
  if (i < np) dst[i] = (i < n) ? a[i] : 0.f;
}

// initial_seq [B][T][IN] fp32 -> xcond hi/lo [T][B][INPAD] bf16 (zero-padded cols)
__global__ void xcond_k(const float* __restrict__ seq, unsigned short* __restrict__ xhi,
                        unsigned short* __restrict__ xlo)
{
  int idx = blockIdx.x * 256 + threadIdx.x;
  const int total = TCOND * BATCH * INPAD;
  if (idx >= total) return;
  int t = idx / (BATCH * INPAD);
  int rem = idx - t * (BATCH * INPAD);
  int b = rem / INPAD;
  int k = rem - b * INPAD;
  float v = (k < INP) ? seq[((size_t)b * TCOND + t) * INP + k] : 0.f;
  unsigned short h = f2bf(v);
  xhi[idx] = h;
  xlo[idx] = f2bf(v - bf2f(h));
}

extern "C" void kernel_launch(void* const* d_in, const int* in_sizes, int n_in,
                              void* d_out, int out_size, void* d_ws, size_t ws_size,
                              hipStream_t stream)
{
  (void)in_sizes; (void)n_in; (void)out_size;
  const float* seq   = (const float*)d_in[0];
  // d_in[1] = generate_frames_number (device scalar) — fixed to 100 by problem spec
  const float* w_ih1 = (const float*)d_in[2];
  const float* w_hh1 = (const float*)d_in[3];
  const float* b_ih1 = (const float*)d_in[4];
  const float* b_hh1 = (const float*)d_in[5];
  const float* w_ih2 = (const float*)d_in[6];
  const float* w_hh2 = (const float*)d_in[7];
  const float* b_ih2 = (const float*)d_in[8];
  const float* b_hh2 = (const float*)d_in[9];
  const float* w_ih3 = (const float*)d_in[10];
  const float* w_hh3 = (const float*)d_in[11];
  const float* b_ih3 = (const float*)d_in[12];
  const float* b_hh3 = (const float*)d_in[13];
  const float* w_dec = (const float*)d_in[14];
  const float* b_dec = (const float*)d_in[15];
  float* out = (float*)d_out;

  char* ws = (char*)d_ws;
  size_t off = 0;
  auto alloc = [&](size_t bytes) -> char* {
    off = (off + 255) & ~(size_t)255;
    char* p = ws + off;
    off += bytes;
    return p;
  };
  auto us = [&](size_t n) { return (unsigned short*)alloc(n * 2); };
  auto fl = [&](size_t n) { return (float*)alloc(n * 4); };

  unsigned short *wx1h = us((size_t)4096 * INPAD), *wx1l = us((size_t)4096 * INPAD);
  unsigned short *wh1h = us((size_t)4096 * HID), *wh1l = us((size_t)4096 * HID);
  unsigned short *wx2h = us((size_t)4096 * HID), *wx2l = us((size_t)4096 * HID);
  unsigned short *wh2h = us((size_t)4096 * HID), *wh2l = us((size_t)4096 * HID);
  unsigned short *wx3h = us((size_t)4096 * HID), *wx3l = us((size_t)4096 * HID);
  unsigned short *wh3h = us((size_t)4096 * HID), *wh3l = us((size_t)4096 * HID);
  unsigned short *wdh = us((size_t)OUTPAD * HID), *wdl = us((size_t)OUTPAD * HID);
  float *b1 = fl(4096), *b2 = fl(4096), *b3 = fl(4096), *bd = fl(OUTPAD);
  unsigned short *xch = us((size_t)TCOND * BATCH * INPAD), *xcl = us((size_t)TCOND * BATCH * INPAD);

  size_t state_beg = (off + 255) & ~(size_t)255;
  float *c0 = fl((size_t)BATCH * HID), *c1 = fl((size_t)BATCH * HID), *c2 = fl((size_t)BATCH * HID);
  unsigned short* Hh[3][2];
  unsigned short* Hl[3][2];
  for (int L = 0; L < 3; ++L)
    for (int p = 0; p < 2; ++p) {
      Hh[L][p] = us((size_t)BATCH * HID);
      Hl[L][p] = us((size_t)BATCH * HID);
    }
  unsigned short *fxh = us((size_t)BATCH * INPAD), *fxl = us((size_t)BATCH * INPAD);
  size_t state_end = off;

  if (off > ws_size) return;  // scratch too small; fail visibly

  // zero all recurrent state (c, h hi/lo both ping-pong buffers, frame incl. pad cols)
  hipMemsetAsync(ws + state_beg, 0, state_end - state_beg, stream);

  // ---- weight / input prep ----
  auto cvt = [&](const float* s, unsigned short* h, unsigned short* l, int R, int C, int Rp, int Cp) {
    int n = Rp * Cp;
    cvt_hilo_k<<<(n + 255) / 256, 256, 0, stream>>>(s, h, l, R, C, Rp, Cp);
  };
  cvt(w_ih1, wx1h, wx1l, 4096, INP, 4096, INPAD);
  cvt(w_hh1, wh1h, wh1l, 4096, HID, 4096, HID);
  cvt(w_ih2, wx2h, wx2l, 4096, HID, 4096, HID);
  cvt(w_hh2, wh2h, wh2l, 4096, HID, 4096, HID);
  cvt(w_ih3, wx3h, wx3l, 4096, HID, 4096, HID);
  cvt(w_hh3, wh3h, wh3l, 4096, HID, 4096, HID);
  cvt(w_dec, wdh, wdl, OUTN, HID, OUTPAD, HID);
  bias2_k<<<16, 256, 0, stream>>>(b_ih1, b_hh1, b1, 4096);
  bias2_k<<<16, 256, 0, stream>>>(b_ih2, b_hh2, b2, 4096);
  bias2_k<<<16, 256, 0, stream>>>(b_ih3, b_hh3, b3, 4096);
  biaspad_k<<<1, 256, 0, stream>>>(b_dec, bd, OUTN, OUTPAD);
  {
    int n = TCOND * BATCH * INPAD;
    xcond_k<<<(n + 255) / 256, 256, 0, stream>>>(seq, xch, xcl);
  }

  // ---- recurrent loop: 50 conditioning + 100 generation steps ----
  for (int s = 0; s < TCOND + GENF; ++s) {
    int pp = s & 1, np = pp ^ 1;
    const unsigned short *xh, *xl;
    if (s < TCOND) {
      xh = xch + (size_t)s * BATCH * INPAD;
      xl = xcl + (size_t)s * BATCH * INPAD;
    } else {
      xh = fxh;
      xl = fxl;
    }
    lstm_layer_k<<<512, 64, 0, stream>>>(xh, xl, INPAD, INPAD, wx1h, wx1l,
        Hh[0][pp], Hl[0][pp], wh1h, wh1l, b1, c0, Hh[0][np], Hl[0][np]);
    lstm_layer_k<<<512, 64, 0, stream>>>(Hh[0][np], Hl[0][np], HID, HID, wx2h, wx2l,
        Hh[1][pp], Hl[1][pp], wh2h, wh2l, b2, c1, Hh[1][np], Hl[1][np]);
    lstm_layer_k<<<512, 64, 0, stream>>>(Hh[1][np], Hl[1][np], HID, HID, wx3h, wx3l,
        Hh[2][pp], Hl[2][pp], wh3h, wh3l, b3, c2, Hh[2][np], Hl[2][np]);
    if (s == TCOND - 1) {
      dec_k<<<88, 64, 0, stream>>>(Hh[2][np], Hl[2][np], wdh, wdl, bd,
                                   (float*)nullptr, fxh, fxl);
    } else if (s >= TCOND) {
      dec_k<<<88, 64, 0, stream>>>(Hh[2][np], Hl[2][np], wdh, wdl, bd,
                                   out + (size_t)(s - TCOND) * OUTN, fxh, fxl);
    }
  }
}